// Round 1
// baseline (1258.781 us; speedup 1.0000x reference)
//
#include <hip/hip_runtime.h>
#include <math.h>

typedef __bf16 bf16;
typedef __attribute__((ext_vector_type(8))) __bf16 bf16x8;
typedef __attribute__((ext_vector_type(4))) float f32x4;

#define M_TOK 4096

// ---------------- conversion kernels ----------------

struct bf16x4s { bf16 a, b, c, d; };

__global__ void cvt_lin(const float* __restrict__ s, bf16* __restrict__ d, long n4) {
  long i = (long)blockIdx.x * blockDim.x + threadIdx.x;
  if (i >= n4) return;
  float4 v = ((const float4*)s)[i];
  bf16x4s o;
  o.a = (bf16)v.x; o.b = (bf16)v.y; o.c = (bf16)v.z; o.d = (bf16)v.w;
  ((bf16x4s*)d)[i] = o;
}

// w3 [10000][16] f32 -> [10048][32] bf16 (K padded to 32; pads stay 0 from memset)
__global__ void cvt_w3k(const float* __restrict__ s, bf16* __restrict__ d) {
  int i = blockIdx.x * 256 + threadIdx.x;
  if (i >= 10000 * 16) return;
  int r = i >> 4, c = i & 15;
  d[r * 32 + c] = (bf16)s[i];
}

// p [1024][N] f32 -> p_t [N][1024] bf16
__global__ void cvt_tr(const float* __restrict__ s, bf16* __restrict__ d, int N, int total) {
  int i = blockIdx.x * 256 + threadIdx.x;
  if (i >= total) return;
  int n = i >> 10, k = i & 1023;
  d[i] = (bf16)s[k * N + n];
}

__global__ void build_headb(const float* __restrict__ b0, const float* __restrict__ cb,
                            float* __restrict__ hb) {
  int i = blockIdx.x * 256 + threadIdx.x;
  if (i >= 10048) return;
  hb[i] = i < 10000 ? b0[i] : (i < 10003 ? cb[i - 10000] : -3.0e38f);
}

__global__ void build_tailb(const float* __restrict__ b, float* __restrict__ tb,
                            int nreal, int npad) {
  int i = blockIdx.x * 256 + threadIdx.x;
  if (i >= npad) return;
  tb[i] = i < nreal ? b[i] : -3.0e38f;
}

// ---------------- GEMM C = A[M,K] * B[N,K]^T, store bf16 ----------------
// block: 512 threads = 8 waves; wave w -> rows rowblk*128 + w*16; one 64-col tile per block.

template<int K>
__global__ __launch_bounds__(512) void gemm_store(
    const bf16* __restrict__ A, const bf16* __restrict__ B,
    bf16* __restrict__ C, int nColTiles, int Nstore) {
  int bx = blockIdx.x;
  int rowblk = bx / nColTiles, tile = bx % nColTiles;
  int tid = threadIdx.x;
  int w = tid >> 6, l = tid & 63;
  int lhi = l >> 4, llo = l & 15;
  int rowbase = rowblk * 128 + w * 16;
  const bf16* Ap = A + (long)(rowbase + llo) * K + lhi * 8;
  int col0 = tile * 64;
  const bf16* Bp = B + (long)(col0 + llo) * K + lhi * 8;
  f32x4 zero = {0.f, 0.f, 0.f, 0.f};
  f32x4 acc[4] = {zero, zero, zero, zero};
  for (int k = 0; k < K; k += 32) {
    bf16x8 a = *(const bf16x8*)(Ap + k);
#pragma unroll
    for (int j = 0; j < 4; ++j) {
      bf16x8 b = *(const bf16x8*)(Bp + (long)j * (16 * K) + k);
      acc[j] = __builtin_amdgcn_mfma_f32_16x16x32_bf16(a, b, acc[j], 0, 0, 0);
    }
  }
  int drow = rowbase + lhi * 4;
#pragma unroll
  for (int j = 0; j < 4; ++j) {
    int col = col0 + j * 16 + llo;
    if (col < Nstore) {
#pragma unroll
      for (int r = 0; r < 4; ++r)
        C[(long)(drow + r) * Nstore + col] = (bf16)acc[j][r];
    }
  }
}

// ---------------- fused GEMM + online logsumexp + gather ----------------
// logits = A[M,K] * B[Npad,K]^T + bias[col]  (bias pads = -3e38)
// Per block: 128 rows x (this split's col tiles). Running (m,s) per row in registers,
// reduced across the 16 lanes of each D-row group via shfl_xor (no LDS).
// Special columns (target / cluster cols) stored by the unique matching lane.

template<int K, int NSPEC>
__global__ __launch_bounds__(512) void gemm_lse(
    const bf16* __restrict__ A, const bf16* __restrict__ B,
    const float* __restrict__ bias, const int* __restrict__ target,
    int nsplits, int tps, int nColTiles,
    int specBase, int specClamp,
    float* __restrict__ Pm, float* __restrict__ Ps, float* __restrict__ Pg) {
  int bx = blockIdx.x;
  int rowblk = bx / nsplits, split = bx % nsplits;
  int tid = threadIdx.x;
  int w = tid >> 6, l = tid & 63;
  int lhi = l >> 4, llo = l & 15;
  int rowbase = rowblk * 128 + w * 16;
  const bf16* Ap = A + (long)(rowbase + llo) * K + lhi * 8;
  long Boff = (long)llo * K + lhi * 8;
  int drow = rowbase + lhi * 4;

  int s0[4];
#pragma unroll
  for (int r = 0; r < 4; ++r) {
    int t = target[drow + r] - specBase;
    s0[r] = t < 0 ? 0 : (t > specClamp ? specClamp : t);
  }

  float m[4] = {-3e38f, -3e38f, -3e38f, -3e38f};
  float s[4] = {0.f, 0.f, 0.f, 0.f};

  int t0 = split * tps;
  int t1 = t0 + tps; if (t1 > nColTiles) t1 = nColTiles;

  for (int tile = t0; tile < t1; ++tile) {
    int col0 = tile * 64;
    const bf16* Bp = B + (long)col0 * K + Boff;
    f32x4 zero = {0.f, 0.f, 0.f, 0.f};
    f32x4 acc[4] = {zero, zero, zero, zero};
    for (int k = 0; k < K; k += 32) {
      bf16x8 a = *(const bf16x8*)(Ap + k);
#pragma unroll
      for (int j = 0; j < 4; ++j) {
        bf16x8 b = *(const bf16x8*)(Bp + (long)j * (16 * K) + k);
        acc[j] = __builtin_amdgcn_mfma_f32_16x16x32_bf16(a, b, acc[j], 0, 0, 0);
      }
    }
    // epilogue: bias + online lse update for this 64-col tile
    float logit[4][4];
    int colj[4];
#pragma unroll
    for (int j = 0; j < 4; ++j) {
      colj[j] = col0 + j * 16 + llo;
      float bj = bias[colj[j]];
#pragma unroll
      for (int r = 0; r < 4; ++r) logit[j][r] = acc[j][r] + bj;
    }
    float mt[4], et[4];
#pragma unroll
    for (int r = 0; r < 4; ++r)
      mt[r] = fmaxf(fmaxf(logit[0][r], logit[1][r]), fmaxf(logit[2][r], logit[3][r]));
#pragma unroll
    for (int off = 1; off < 16; off <<= 1) {
#pragma unroll
      for (int r = 0; r < 4; ++r)
        mt[r] = fmaxf(mt[r], __shfl_xor(mt[r], off));
    }
#pragma unroll
    for (int r = 0; r < 4; ++r)
      et[r] = __expf(logit[0][r] - mt[r]) + __expf(logit[1][r] - mt[r]) +
              __expf(logit[2][r] - mt[r]) + __expf(logit[3][r] - mt[r]);
#pragma unroll
    for (int off = 1; off < 16; off <<= 1) {
#pragma unroll
      for (int r = 0; r < 4; ++r)
        et[r] += __shfl_xor(et[r], off);
    }
#pragma unroll
    for (int r = 0; r < 4; ++r) {
      float mn = fmaxf(m[r], mt[r]);
      s[r] = s[r] * __expf(m[r] - mn) + et[r] * __expf(mt[r] - mn);
      m[r] = mn;
    }
    // specials: unique matching lane stores directly (slots pre-zeroed by memset)
#pragma unroll
    for (int j = 0; j < 4; ++j) {
#pragma unroll
      for (int r = 0; r < 4; ++r) {
        if (colj[j] == s0[r]) Pg[drow + r] = logit[j][r];
        if (NSPEC > 1) {
#pragma unroll
          for (int q = 1; q < NSPEC; ++q)
            if (colj[j] == 9999 + q) Pg[q * M_TOK + drow + r] = logit[j][r];
        }
      }
    }
  }

  if (llo == 0) {
#pragma unroll
    for (int r = 0; r < 4; ++r) {
      Pm[split * M_TOK + drow + r] = m[r];
      Ps[split * M_TOK + drow + r] = s[r];
    }
  }
}

// ---------------- final: merge partials, per-token lp, mean ----------------

__global__ __launch_bounds__(512) void final_reduce(
    const int* __restrict__ target,
    const float* __restrict__ hm, const float* __restrict__ hsv,
    const float* __restrict__ hg, int HS,
    const float* __restrict__ m1, const float* __restrict__ s1v,
    const float* __restrict__ g1, int S1,
    const float* __restrict__ m2, const float* __restrict__ s2v,
    const float* __restrict__ g2, int S2,
    const float* __restrict__ m3, const float* __restrict__ s3v,
    const float* __restrict__ g3, int S3,
    float* __restrict__ out) {
  __shared__ float red[512];
  float local = 0.f;
  for (int row = threadIdx.x; row < M_TOK; row += 512) {
    float mh = -3e38f;
    for (int sp = 0; sp < HS; ++sp) mh = fmaxf(mh, hm[sp * M_TOK + row]);
    float sh = 0.f;
    for (int sp = 0; sp < HS; ++sp) sh += hsv[sp * M_TOK + row] * expf(hm[sp * M_TOK + row] - mh);
    float lseh = mh + logf(sh);
    int t = target[row];
    float lp;
    if (t < 10000) {
      lp = hg[row] - lseh;
    } else {
      const float* tm; const float* ts; const float* tg; int S; int q;
      if (t < 20000)      { tm = m1; ts = s1v; tg = g1; S = S1; q = 3; }
      else if (t < 40000) { tm = m2; ts = s2v; tg = g2; S = S2; q = 2; }
      else                { tm = m3; ts = s3v; tg = g3; S = S3; q = 1; }
      float mm = -3e38f;
      for (int sp = 0; sp < S; ++sp) mm = fmaxf(mm, tm[sp * M_TOK + row]);
      float ss = 0.f;
      for (int sp = 0; sp < S; ++sp) ss += ts[sp * M_TOK + row] * expf(tm[sp * M_TOK + row] - mm);
      float lset = mm + logf(ss);
      lp = (hg[q * M_TOK + row] - lseh) + (tg[row] - lset);
    }
    local += lp;
  }
  red[threadIdx.x] = local;
  __syncthreads();
  for (int o = 256; o > 0; o >>= 1) {
    if (threadIdx.x < o) red[threadIdx.x] += red[threadIdx.x + o];
    __syncthreads();
  }
  if (threadIdx.x == 0) out[0] = -red[0] / (float)M_TOK;
}

// ---------------- host ----------------

extern "C" void kernel_launch(void* const* d_in, const int* in_sizes, int n_in,
                              void* d_out, int out_size, void* d_ws, size_t ws_size,
                              hipStream_t stream) {
  const float* hidden = (const float*)d_in[0];
  const int*   target = (const int*)d_in[1];
  const float* w0 = (const float*)d_in[2];
  const float* b0 = (const float*)d_in[3];
  const float* p0 = (const float*)d_in[4];
  const float* w1 = (const float*)d_in[5];
  const float* b1 = (const float*)d_in[6];
  const float* p1 = (const float*)d_in[7];
  const float* w2 = (const float*)d_in[8];
  const float* b2 = (const float*)d_in[9];
  const float* p2 = (const float*)d_in[10];
  const float* w3 = (const float*)d_in[11];
  const float* b3 = (const float*)d_in[12];
  const float* p3 = (const float*)d_in[13];
  const float* cw = (const float*)d_in[14];
  const float* cb = (const float*)d_in[15];

  char* ws = (char*)d_ws;
  size_t off = 0;
  auto alloc = [&](size_t bytes) -> char* {
    char* p = ws + off;
    off += (bytes + 255) & ~(size_t)255;
    return p;
  };
  bf16* hiddenB = (bf16*)alloc(4096L * 1024 * 2);
  bf16* p0t   = (bf16*)alloc(1024L * 1024 * 2);
  bf16* p1t   = (bf16*)alloc(256L * 1024 * 2);
  bf16* p2t   = (bf16*)alloc(64L * 1024 * 2);
  bf16* p3t   = (bf16*)alloc(64L * 1024 * 2);
  bf16* headw = (bf16*)alloc(10048L * 1024 * 2);
  bf16* w1p   = (bf16*)alloc(10048L * 256 * 2);
  bf16* w2p   = (bf16*)alloc(20032L * 64 * 2);
  bf16* w3p   = (bf16*)alloc(10048L * 32 * 2);
  bf16* proj0 = (bf16*)alloc(4096L * 1024 * 2);
  bf16* proj1 = (bf16*)alloc(4096L * 256 * 2);
  bf16* proj2 = (bf16*)alloc(4096L * 64 * 2);
  bf16* proj3 = (bf16*)alloc(4096L * 32 * 2);
  float* headb = (float*)alloc(10048L * 4);
  float* t1b   = (float*)alloc(10048L * 4);
  float* t2b   = (float*)alloc(20032L * 4);
  float* t3b   = (float*)alloc(10048L * 4);
  const int HS = 16, S1 = 16, S2 = 32, S3 = 16;
  float* hm  = (float*)alloc((size_t)HS * M_TOK * 4);
  float* hsv = (float*)alloc((size_t)HS * M_TOK * 4);
  float* hg  = (float*)alloc(4L * M_TOK * 4);
  float* m1  = (float*)alloc((size_t)S1 * M_TOK * 4);
  float* s1v = (float*)alloc((size_t)S1 * M_TOK * 4);
  float* g1  = (float*)alloc((size_t)M_TOK * 4);
  float* m2  = (float*)alloc((size_t)S2 * M_TOK * 4);
  float* s2v = (float*)alloc((size_t)S2 * M_TOK * 4);
  float* g2  = (float*)alloc((size_t)M_TOK * 4);
  float* m3  = (float*)alloc((size_t)S3 * M_TOK * 4);
  float* s3v = (float*)alloc((size_t)S3 * M_TOK * 4);
  float* g3  = (float*)alloc((size_t)M_TOK * 4);
  size_t total = off;
  if (ws_size < total) return;  // would corrupt; fail cleanly instead

  hipMemsetAsync(d_ws, 0, total, stream);

  // conversions (pads remain zero from memset)
  cvt_lin<<<(4096 * 1024 / 4 + 255) / 256, 256, 0, stream>>>(hidden, hiddenB, 4096L * 1024 / 4);
  cvt_lin<<<(10000 * 1024 / 4 + 255) / 256, 256, 0, stream>>>(w0, headw, 10000L * 1024 / 4);
  cvt_lin<<<(3 * 1024 / 4 + 255) / 256, 256, 0, stream>>>(cw, headw + 10000L * 1024, 3L * 1024 / 4);
  cvt_lin<<<(10000 * 256 / 4 + 255) / 256, 256, 0, stream>>>(w1, w1p, 10000L * 256 / 4);
  cvt_lin<<<(20000 * 64 / 4 + 255) / 256, 256, 0, stream>>>(w2, w2p, 20000L * 64 / 4);
  cvt_w3k<<<(160000 + 255) / 256, 256, 0, stream>>>(w3, w3p);
  cvt_tr<<<(1024 * 1024 + 255) / 256, 256, 0, stream>>>(p0, p0t, 1024, 1024 * 1024);
  cvt_tr<<<(256 * 1024 + 255) / 256, 256, 0, stream>>>(p1, p1t, 256, 256 * 1024);
  cvt_tr<<<(64 * 1024 + 255) / 256, 256, 0, stream>>>(p2, p2t, 64, 64 * 1024);
  cvt_tr<<<(16 * 1024 + 255) / 256, 256, 0, stream>>>(p3, p3t, 16, 16 * 1024);
  build_headb<<<(10048 + 255) / 256, 256, 0, stream>>>(b0, cb, headb);
  build_tailb<<<(10048 + 255) / 256, 256, 0, stream>>>(b1, t1b, 10000, 10048);
  build_tailb<<<(20032 + 255) / 256, 256, 0, stream>>>(b2, t2b, 20000, 20032);
  build_tailb<<<(10048 + 255) / 256, 256, 0, stream>>>(b3, t3b, 10000, 10048);

  // projections: proj_c = hidden @ p_c  (bf16 out)
  gemm_store<1024><<<32 * 16, 512, 0, stream>>>(hiddenB, p0t, proj0, 16, 1024);
  gemm_store<1024><<<32 * 4, 512, 0, stream>>>(hiddenB, p1t, proj1, 4, 256);
  gemm_store<1024><<<32 * 1, 512, 0, stream>>>(hiddenB, p2t, proj2, 1, 64);
  gemm_store<1024><<<32 * 1, 512, 0, stream>>>(hiddenB, p3t, proj3, 1, 32);

  // fused logits + online logsumexp + gathers
  gemm_lse<1024, 4><<<32 * HS, 512, 0, stream>>>(proj0, headw, headb, target,
                                                 HS, 10, 157, 0, 9999, hm, hsv, hg);
  gemm_lse<256, 1><<<32 * S1, 512, 0, stream>>>(proj1, w1p, t1b, target,
                                                S1, 10, 157, 10000, 9999, m1, s1v, g1);
  gemm_lse<64, 1><<<32 * S2, 512, 0, stream>>>(proj2, w2p, t2b, target,
                                               S2, 10, 313, 20000, 19999, m2, s2v, g2);
  gemm_lse<32, 1><<<32 * S3, 512, 0, stream>>>(proj3, w3p, t3b, target,
                                               S3, 10, 157, 40000, 9999, m3, s3v, g3);

  final_reduce<<<1, 512, 0, stream>>>(target, hm, hsv, hg, HS,
                                      m1, s1v, g1, S1, m2, s2v, g2, S2,
                                      m3, s3v, g3, S3, (float*)d_out);
}

// Round 2
// 622.712 us; speedup vs baseline: 2.0215x; 2.0215x over previous
//
#include <hip/hip_runtime.h>
#include <math.h>

typedef __bf16 bf16;
typedef __attribute__((ext_vector_type(8))) __bf16 bf16x8;
typedef __attribute__((ext_vector_type(4))) float f32x4;

#define M_TOK 4096

// ---------------- helpers ----------------

__device__ __forceinline__ void gl_lds16(const bf16* g, bf16* l) {
  __builtin_amdgcn_global_load_lds(
      (const __attribute__((address_space(1))) unsigned int*)g,
      (__attribute__((address_space(3))) unsigned int*)l, 16, 0, 0);
}

// bijective XCD swizzle (m204)
__device__ __forceinline__ int xcd_swz(int idx, int nwg) {
  int xcd = idx & 7, pos = idx >> 3;
  int q = nwg >> 3, r = nwg & 7;
  int base = xcd < r ? xcd * (q + 1) : r * (q + 1) + (xcd - r) * q;
  return base + pos;
}

// ---------------- conversion kernels ----------------

struct bf16x4s { bf16 a, b, c, d; };

__global__ void cvt_lin(const float* __restrict__ s, bf16* __restrict__ d, long n4) {
  long i = (long)blockIdx.x * blockDim.x + threadIdx.x;
  if (i >= n4) return;
  float4 v = ((const float4*)s)[i];
  bf16x4s o;
  o.a = (bf16)v.x; o.b = (bf16)v.y; o.c = (bf16)v.z; o.d = (bf16)v.w;
  ((bf16x4s*)d)[i] = o;
}

// w3 [10000][16] f32 -> [10112][32] bf16 (K padded to 32; pads pre-zeroed)
__global__ void cvt_w3k(const float* __restrict__ s, bf16* __restrict__ d) {
  int i = blockIdx.x * 256 + threadIdx.x;
  if (i >= 10000 * 16) return;
  int r = i >> 4, c = i & 15;
  d[r * 32 + c] = (bf16)s[i];
}

// p [1024][N] f32 -> p_t [N][1024] bf16
__global__ void cvt_tr(const float* __restrict__ s, bf16* __restrict__ d, int N, int total) {
  int i = blockIdx.x * 256 + threadIdx.x;
  if (i >= total) return;
  int n = i >> 10, k = i & 1023;
  d[i] = (bf16)s[k * N + n];
}

__global__ void build_headb(const float* __restrict__ b0, const float* __restrict__ cb,
                            float* __restrict__ hb, int npad) {
  int i = blockIdx.x * 256 + threadIdx.x;
  if (i >= npad) return;
  hb[i] = i < 10000 ? b0[i] : (i < 10003 ? cb[i - 10000] : -3.0e38f);
}

__global__ void build_tailb(const float* __restrict__ b, float* __restrict__ tb,
                            int nreal, int npad) {
  int i = blockIdx.x * 256 + threadIdx.x;
  if (i >= npad) return;
  tb[i] = i < nreal ? b[i] : -3.0e38f;
}

// ---------------- staged 128x128 GEMM (m97 structure) ----------------
// C = A[M,K] * B[Npad,K]^T (+bias).  256 thr = 4 waves, each wave one 64x64
// quadrant (4x4 fragments of 16x16x32 MFMA). BK=32, global_load_lds staging.
// MODE 0: store bf16 C.  MODE 1: per-tile LSE partials with online merge
// across this block's tiles; specials scattered directly.

template<int K, int MODE, int NSPEC>
__global__ __launch_bounds__(256) void gemm128(
    const bf16* __restrict__ A, int lda,
    const bf16* __restrict__ B, int nTiles, int tpb,
    bf16* __restrict__ C, int ldc, int nstore,
    const float* __restrict__ bias, const int* __restrict__ target,
    int specBase, int specClamp,
    float* __restrict__ Pm, float* __restrict__ Ps, float* __restrict__ Pg) {
  int nsplits = (nTiles + tpb - 1) / tpb;
  int nwg = nsplits * 32;
  int wg = xcd_swz(blockIdx.x, nwg);
  int split = wg >> 5;      // col-split major -> per-XCD chunk keeps B slice L2-hot
  int rowblk = wg & 31;
  int tid = threadIdx.x;
  int w = tid >> 6, llo = tid & 15, lhi = (tid >> 4) & 3;
  int wr = w >> 1, wc = w & 1;
  int rowbase = rowblk * 128;

  __shared__ bf16 As[128 * 32];
  __shared__ bf16 Bs[128 * 32];

  // staging: thread t covers 16B at LDS byte t*16 (linear, wave-uniform + lane*16)
  int srow = tid >> 2;
  int selem = (tid & 3) * 8;
  const bf16* ga0 = A + (long)(rowbase + srow) * lda + selem;
  const bf16* ga1 = ga0 + (long)64 * lda;
  bf16* la0 = As + tid * 8;
  bf16* la1 = As + 2048 + tid * 8;
  bf16* lb0 = Bs + tid * 8;
  bf16* lb1 = Bs + 2048 + tid * 8;

  float rm[4][4], rs[4][4];
#pragma unroll
  for (int a = 0; a < 4; ++a)
#pragma unroll
    for (int b = 0; b < 4; ++b) { rm[a][b] = -3e38f; rs[a][b] = 0.f; }

  int t0 = split * tpb;
  int tE = t0 + tpb; if (tE > nTiles) tE = nTiles;

  for (int tile = t0; tile < tE; ++tile) {
    int col0 = tile * 128;
    const bf16* gb0 = B + (long)(col0 + srow) * K + selem;
    const bf16* gb1 = gb0 + (long)64 * K;

    f32x4 acc[4][4];
    f32x4 zero = {0.f, 0.f, 0.f, 0.f};
#pragma unroll
    for (int a = 0; a < 4; ++a)
#pragma unroll
      for (int b = 0; b < 4; ++b) acc[a][b] = zero;

    for (int k0 = 0; k0 < K; k0 += 32) {
      gl_lds16(ga0 + k0, la0);
      gl_lds16(ga1 + k0, la1);
      gl_lds16(gb0 + k0, lb0);
      gl_lds16(gb1 + k0, lb1);
      __syncthreads();
      bf16x8 af[4], bf_[4];
#pragma unroll
      for (int m = 0; m < 4; ++m)
        af[m] = *(const bf16x8*)(As + (wr * 64 + m * 16 + llo) * 32 + lhi * 8);
#pragma unroll
      for (int n = 0; n < 4; ++n)
        bf_[n] = *(const bf16x8*)(Bs + (wc * 64 + n * 16 + llo) * 32 + lhi * 8);
#pragma unroll
      for (int m = 0; m < 4; ++m)
#pragma unroll
        for (int n = 0; n < 4; ++n)
          acc[m][n] = __builtin_amdgcn_mfma_f32_16x16x32_bf16(af[m], bf_[n], acc[m][n], 0, 0, 0);
      __syncthreads();
    }

    if (MODE == 0) {
#pragma unroll
      for (int m = 0; m < 4; ++m) {
        int row = rowbase + wr * 64 + m * 16 + lhi * 4;
#pragma unroll
        for (int n = 0; n < 4; ++n) {
          int col = col0 + wc * 64 + n * 16 + llo;
          if (col < nstore) {
#pragma unroll
            for (int r = 0; r < 4; ++r)
              C[(long)(row + r) * ldc + col] = (bf16)acc[m][n][r];
          }
        }
      }
    } else {
      float bv[4];
#pragma unroll
      for (int n = 0; n < 4; ++n) bv[n] = bias[col0 + wc * 64 + n * 16 + llo];
#pragma unroll
      for (int mm = 0; mm < 4; ++mm) {
        int rbase = rowbase + wr * 64 + mm * 16 + lhi * 4;
        float v[4][4];
#pragma unroll
        for (int r = 0; r < 4; ++r)
#pragma unroll
          for (int n = 0; n < 4; ++n) v[r][n] = acc[mm][n][r] + bv[n];
        float mt[4], et[4];
#pragma unroll
        for (int r = 0; r < 4; ++r)
          mt[r] = fmaxf(fmaxf(v[r][0], v[r][1]), fmaxf(v[r][2], v[r][3]));
#pragma unroll
        for (int off = 1; off < 16; off <<= 1)
#pragma unroll
          for (int r = 0; r < 4; ++r) mt[r] = fmaxf(mt[r], __shfl_xor(mt[r], off));
#pragma unroll
        for (int r = 0; r < 4; ++r)
          et[r] = __expf(v[r][0] - mt[r]) + __expf(v[r][1] - mt[r]) +
                  __expf(v[r][2] - mt[r]) + __expf(v[r][3] - mt[r]);
#pragma unroll
        for (int off = 1; off < 16; off <<= 1)
#pragma unroll
          for (int r = 0; r < 4; ++r) et[r] += __shfl_xor(et[r], off);
        // online merge into block-running (m,s)
#pragma unroll
        for (int r = 0; r < 4; ++r) {
          float mn = fmaxf(rm[mm][r], mt[r]);
          rs[mm][r] = rs[mm][r] * __expf(rm[mm][r] - mn) + et[r] * __expf(mt[r] - mn);
          rm[mm][r] = mn;
        }
        // special-column scatter (target col; head cluster cols 10000..10002)
#pragma unroll
        for (int r = 0; r < 4; ++r) {
          int row = rbase + r;
          int tg = target[row] - specBase;
          int sc = tg < 0 ? 0 : (tg > specClamp ? specClamp : tg);
#pragma unroll
          for (int n = 0; n < 4; ++n) {
            int col = col0 + wc * 64 + n * 16 + llo;
            if (col == sc) Pg[row] = v[r][n];
            if (NSPEC > 1) {
#pragma unroll
              for (int q = 1; q < NSPEC; ++q)
                if (col == 9999 + q) Pg[(long)q * M_TOK + row] = v[r][n];
            }
          }
        }
      }
    }
  }

  if (MODE == 1 && llo == 0) {
    // one partial slot per (split, column-half wc) -- the two wc waves cover
    // different columns of the same rows and must not collide.
#pragma unroll
    for (int mm = 0; mm < 4; ++mm) {
      int rbase = rowbase + wr * 64 + mm * 16 + lhi * 4;
      long slot = (long)(split * 2 + wc) * M_TOK;
#pragma unroll
      for (int r = 0; r < 4; ++r) {
        Pm[slot + rbase + r] = rm[mm][r];
        Ps[slot + rbase + r] = rs[mm][r];
      }
    }
  }
}

// ---------------- merge partials -> per-token lp ----------------
// one wave per row; lanes stride over split slots; (m,s)-pair shfl merge.

__global__ __launch_bounds__(256) void merge_lp(
    const int* __restrict__ target,
    const float* __restrict__ hm, const float* __restrict__ hs,
    const float* __restrict__ hg, int HT,
    const float* __restrict__ m1, const float* __restrict__ s1,
    const float* __restrict__ g1, int T1,
    const float* __restrict__ m2, const float* __restrict__ s2,
    const float* __restrict__ g2, int T2,
    const float* __restrict__ m3, const float* __restrict__ s3,
    const float* __restrict__ g3, int T3,
    float* __restrict__ lp) {
  int lane = threadIdx.x & 63;
  int row = (blockIdx.x * 256 + threadIdx.x) >> 6;
  if (row >= M_TOK) return;

  float mm = -3e38f, ss = 0.f;
  for (int sp = lane; sp < HT; sp += 64) {
    float mi = hm[(long)sp * M_TOK + row];
    float si = hs[(long)sp * M_TOK + row];
    float mn = fmaxf(mm, mi);
    ss = ss * __expf(mm - mn) + si * __expf(mi - mn);
    mm = mn;
  }
#pragma unroll
  for (int off = 1; off < 64; off <<= 1) {
    float mo = __shfl_xor(mm, off), so = __shfl_xor(ss, off);
    float mn = fmaxf(mm, mo);
    ss = ss * __expf(mm - mn) + so * __expf(mo - mn);
    mm = mn;
  }
  float lseh = mm + __logf(ss);

  int t = target[row];
  float res;
  if (t < 10000) {
    res = hg[row] - lseh;
  } else {
    const float* tm; const float* ts; const float* tg; int T; int q;
    if (t < 20000)      { tm = m1; ts = s1; tg = g1; T = T1; q = 3; }
    else if (t < 40000) { tm = m2; ts = s2; tg = g2; T = T2; q = 2; }
    else                { tm = m3; ts = s3; tg = g3; T = T3; q = 1; }
    float ma = -3e38f, sa = 0.f;
    for (int sp = lane; sp < T; sp += 64) {
      float mi = tm[(long)sp * M_TOK + row];
      float si = ts[(long)sp * M_TOK + row];
      float mn = fmaxf(ma, mi);
      sa = sa * __expf(ma - mn) + si * __expf(mi - mn);
      ma = mn;
    }
#pragma unroll
    for (int off = 1; off < 64; off <<= 1) {
      float mo = __shfl_xor(ma, off), so = __shfl_xor(sa, off);
      float mn = fmaxf(ma, mo);
      sa = sa * __expf(ma - mn) + so * __expf(mo - mn);
      ma = mn;
    }
    float lset = ma + __logf(sa);
    res = (hg[(long)q * M_TOK + row] - lseh) + (tg[row] - lset);
  }
  if (lane == 0) lp[row] = res;
}

__global__ void neg_mean(const float* __restrict__ lp, float* __restrict__ out) {
  __shared__ float red[256];
  float s = 0.f;
  for (int i = threadIdx.x; i < M_TOK; i += 256) s += lp[i];
  red[threadIdx.x] = s;
  __syncthreads();
  for (int o = 128; o > 0; o >>= 1) {
    if (threadIdx.x < o) red[threadIdx.x] += red[threadIdx.x + o];
    __syncthreads();
  }
  if (threadIdx.x == 0) out[0] = -red[0] / (float)M_TOK;
}

// ---------------- host ----------------

extern "C" void kernel_launch(void* const* d_in, const int* in_sizes, int n_in,
                              void* d_out, int out_size, void* d_ws, size_t ws_size,
                              hipStream_t stream) {
  const float* hidden = (const float*)d_in[0];
  const int*   target = (const int*)d_in[1];
  const float* w0 = (const float*)d_in[2];
  const float* b0 = (const float*)d_in[3];
  const float* p0 = (const float*)d_in[4];
  const float* w1 = (const float*)d_in[5];
  const float* b1 = (const float*)d_in[6];
  const float* p1 = (const float*)d_in[7];
  const float* w2 = (const float*)d_in[8];
  const float* b2 = (const float*)d_in[9];
  const float* p2 = (const float*)d_in[10];
  const float* w3 = (const float*)d_in[11];
  const float* b3 = (const float*)d_in[12];
  const float* p3 = (const float*)d_in[13];
  const float* cw = (const float*)d_in[14];
  const float* cb = (const float*)d_in[15];

  // padded col counts (multiples of 128)
  const int NH = 10112, N1 = 10112, N2 = 20096, N3 = 10112;
  const int TH = NH / 128, T1t = N1 / 128, T2t = N2 / 128, T3t = N3 / 128; // 79,79,157,79
  const int TPB = 4;
  const int SH = (TH + TPB - 1) / TPB;   // 20
  const int S1 = (T1t + TPB - 1) / TPB;  // 20
  const int S2 = (T2t + TPB - 1) / TPB;  // 40
  const int S3 = (T3t + TPB - 1) / TPB;  // 20

  char* ws = (char*)d_ws;
  size_t off = 0;
  auto alloc = [&](size_t bytes) -> char* {
    char* p = ws + off;
    off += (bytes + 255) & ~(size_t)255;
    return p;
  };
  bf16* hiddenB = (bf16*)alloc(4096L * 1024 * 2);
  bf16* p0t   = (bf16*)alloc(1024L * 1024 * 2);
  bf16* pAll  = (bf16*)alloc(384L * 1024 * 2);   // p1(0..255) p2(256..319) p3(320..335) pad..383
  bf16* headw = (bf16*)alloc((long)NH * 1024 * 2);
  bf16* w1p   = (bf16*)alloc((long)N1 * 256 * 2);
  bf16* w2p   = (bf16*)alloc((long)N2 * 64 * 2);
  bf16* w3p   = (bf16*)alloc((long)N3 * 32 * 2);
  bf16* proj0   = (bf16*)alloc(4096L * 1024 * 2);
  bf16* projAll = (bf16*)alloc(4096L * 384 * 2);
  float* headb = (float*)alloc((long)NH * 4);
  float* t1b   = (float*)alloc((long)N1 * 4);
  float* t2b   = (float*)alloc((long)N2 * 4);
  float* t3b   = (float*)alloc((long)N3 * 4);
  float* hm  = (float*)alloc((size_t)SH * 2 * M_TOK * 4);
  float* hsv = (float*)alloc((size_t)SH * 2 * M_TOK * 4);
  float* hg  = (float*)alloc(4L * M_TOK * 4);
  float* m1  = (float*)alloc((size_t)S1 * 2 * M_TOK * 4);
  float* s1v = (float*)alloc((size_t)S1 * 2 * M_TOK * 4);
  float* g1  = (float*)alloc((size_t)M_TOK * 4);
  float* m2  = (float*)alloc((size_t)S2 * 2 * M_TOK * 4);
  float* s2v = (float*)alloc((size_t)S2 * 2 * M_TOK * 4);
  float* g2  = (float*)alloc((size_t)M_TOK * 4);
  float* m3  = (float*)alloc((size_t)S3 * 2 * M_TOK * 4);
  float* s3v = (float*)alloc((size_t)S3 * 2 * M_TOK * 4);
  float* g3  = (float*)alloc((size_t)M_TOK * 4);
  float* lp  = (float*)alloc((size_t)M_TOK * 4);
  if (ws_size < off) return;  // fail cleanly rather than corrupt

  // targeted pad zeroing (everything else is fully overwritten each call)
  hipMemsetAsync(headw + 10003L * 1024, 0, (NH - 10003L) * 1024 * 2, stream);
  hipMemsetAsync(w1p + 10000L * 256, 0, (N1 - 10000L) * 256 * 2, stream);
  hipMemsetAsync(w2p + 20000L * 64, 0, (N2 - 20000L) * 64 * 2, stream);
  hipMemsetAsync(w3p, 0, (long)N3 * 32 * 2, stream);
  hipMemsetAsync(pAll + 336L * 1024, 0, 48L * 1024 * 2, stream);

  // conversions
  cvt_lin<<<(4096 * 1024 / 4 + 255) / 256, 256, 0, stream>>>(hidden, hiddenB, 4096L * 1024 / 4);
  cvt_lin<<<(10000 * 1024 / 4 + 255) / 256, 256, 0, stream>>>(w0, headw, 10000L * 1024 / 4);
  cvt_lin<<<(3 * 1024 / 4 + 255) / 256, 256, 0, stream>>>(cw, headw + 10000L * 1024, 3L * 1024 / 4);
  cvt_lin<<<(10000 * 256 / 4 + 255) / 256, 256, 0, stream>>>(w1, w1p, 10000L * 256 / 4);
  cvt_lin<<<(20000 * 64 / 4 + 255) / 256, 256, 0, stream>>>(w2, w2p, 20000L * 64 / 4);
  cvt_w3k<<<(160000 + 255) / 256, 256, 0, stream>>>(w3, w3p);
  cvt_tr<<<(1024 * 1024 + 255) / 256, 256, 0, stream>>>(p0, p0t, 1024, 1024 * 1024);
  cvt_tr<<<(256 * 1024 + 255) / 256, 256, 0, stream>>>(p1, pAll, 256, 256 * 1024);
  cvt_tr<<<(64 * 1024 + 255) / 256, 256, 0, stream>>>(p2, pAll + 256L * 1024, 64, 64 * 1024);
  cvt_tr<<<(16 * 1024 + 255) / 256, 256, 0, stream>>>(p3, pAll + 320L * 1024, 16, 16 * 1024);
  build_headb<<<(NH + 255) / 256, 256, 0, stream>>>(b0, cb, headb, NH);
  build_tailb<<<(N1 + 255) / 256, 256, 0, stream>>>(b1, t1b, 10000, N1);
  build_tailb<<<(N2 + 255) / 256, 256, 0, stream>>>(b2, t2b, 20000, N2);
  build_tailb<<<(N3 + 255) / 256, 256, 0, stream>>>(b3, t3b, 10000, N3);

  // projections (MODE 0): proj0 = hidden@p0 ; projAll = hidden@[p1|p2|p3]
  gemm128<1024, 0, 1><<<8 * 32, 256, 0, stream>>>(
      hiddenB, 1024, p0t, 8, 1, proj0, 1024, 1024,
      nullptr, nullptr, 0, 0, nullptr, nullptr, nullptr);
  gemm128<1024, 0, 1><<<3 * 32, 256, 0, stream>>>(
      hiddenB, 1024, pAll, 3, 1, projAll, 384, 384,
      nullptr, nullptr, 0, 0, nullptr, nullptr, nullptr);

  // fused logits + LSE partials + gathers (MODE 1)
  gemm128<1024, 1, 4><<<SH * 32, 256, 0, stream>>>(
      proj0, 1024, headw, TH, TPB, nullptr, 0, 0,
      headb, target, 0, 9999, hm, hsv, hg);
  gemm128<256, 1, 1><<<S1 * 32, 256, 0, stream>>>(
      projAll, 384, w1p, T1t, TPB, nullptr, 0, 0,
      t1b, target, 10000, 9999, m1, s1v, g1);
  gemm128<64, 1, 1><<<S2 * 32, 256, 0, stream>>>(
      projAll + 256, 384, w2p, T2t, TPB, nullptr, 0, 0,
      t2b, target, 20000, 19999, m2, s2v, g2);
  gemm128<32, 1, 1><<<S3 * 32, 256, 0, stream>>>(
      projAll + 320, 384, w3p, T3t, TPB, nullptr, 0, 0,
      t3b, target, 40000, 9999, m3, s3v, g3);

  merge_lp<<<1024, 256, 0, stream>>>(target,
      hm, hsv, hg, SH * 2, m1, s1v, g1, S1 * 2,
      m2, s2v, g2, S2 * 2, m3, s3v, g3, S3 * 2, lp);
  neg_mean<<<1, 256, 0, stream>>>(lp, (float*)d_out);
}

// Round 3
// 295.397 us; speedup vs baseline: 4.2613x; 2.1080x over previous
//
#include <hip/hip_runtime.h>
#include <math.h>

typedef __bf16 bf16;
typedef __attribute__((ext_vector_type(8))) __bf16 bf16x8;
typedef __attribute__((ext_vector_type(4))) float f32x4;

#define M_TOK 4096
#define MREF 8.0f   // fixed logsumexp reference point (logits bounded ~|4|)

// ---------------- helpers ----------------

__device__ __forceinline__ void gl_lds16(const bf16* g, bf16* l) {
  __builtin_amdgcn_global_load_lds(
      (const __attribute__((address_space(1))) unsigned int*)g,
      (__attribute__((address_space(3))) unsigned int*)l, 16, 0, 0);
}

// bijective XCD swizzle (m204)
__device__ __forceinline__ int xcd_swz(int idx, int nwg) {
  int xcd = idx & 7, pos = idx >> 3;
  int q = nwg >> 3, r = nwg & 7;
  int base = xcd < r ? xcd * (q + 1) : r * (q + 1) + (xcd - r) * q;
  return base + pos;
}

// ---------------- conversion kernels ----------------

struct bf16x4s { bf16 a, b, c, d; };

__global__ void cvt_lin(const float* __restrict__ s, bf16* __restrict__ d, long n4) {
  long i = (long)blockIdx.x * blockDim.x + threadIdx.x;
  if (i >= n4) return;
  float4 v = ((const float4*)s)[i];
  bf16x4s o;
  o.a = (bf16)v.x; o.b = (bf16)v.y; o.c = (bf16)v.z; o.d = (bf16)v.w;
  ((bf16x4s*)d)[i] = o;
}

// w3 [10000][16] f32 -> [10112][32] bf16 (K padded to 32; pads pre-zeroed)
__global__ void cvt_w3k(const float* __restrict__ s, bf16* __restrict__ d) {
  int i = blockIdx.x * 256 + threadIdx.x;
  if (i >= 10000 * 16) return;
  int r = i >> 4, c = i & 15;
  d[r * 32 + c] = (bf16)s[i];
}

// LDS-tiled transpose+cvt: s[1024][N] f32 -> d[n][1024] bf16 (both coalesced)
__global__ void tr_cvt(const float* __restrict__ s, bf16* __restrict__ d, int N) {
  __shared__ float tile[64][65];
  int kb = blockIdx.x * 64, nb = blockIdx.y * 64;
  int tx = threadIdx.x & 63, ty = threadIdx.x >> 6;
  if (nb + tx < N) {
#pragma unroll
    for (int kk = ty; kk < 64; kk += 4)
      tile[kk][tx] = s[(long)(kb + kk) * N + nb + tx];
  }
  __syncthreads();
#pragma unroll
  for (int nn = ty; nn < 64; nn += 4) {
    if (nb + nn < N)
      d[(long)(nb + nn) * 1024 + kb + tx] = (bf16)tile[tx][nn];
  }
}

// all four bias arrays in one launch (pads = -3e38)
__global__ void build_bias(const float* __restrict__ b0, const float* __restrict__ cb,
                           const float* __restrict__ b1, const float* __restrict__ b2,
                           const float* __restrict__ b3,
                           float* __restrict__ hb, float* __restrict__ t1,
                           float* __restrict__ t2, float* __restrict__ t3,
                           int NH, int N1, int N2, int N3) {
  int i = blockIdx.x * 256 + threadIdx.x;
  if (i < NH) {
    hb[i] = i < 10000 ? b0[i] : (i < 10003 ? cb[i - 10000] : -3.0e38f);
  } else if (i < NH + N1) {
    int j = i - NH; t1[j] = j < 10000 ? b1[j] : -3.0e38f;
  } else if (i < NH + N1 + N2) {
    int j = i - NH - N1; t2[j] = j < 20000 ? b2[j] : -3.0e38f;
  } else if (i < NH + N1 + N2 + N3) {
    int j = i - NH - N1 - N2; t3[j] = j < 10000 ? b3[j] : -3.0e38f;
  }
}

// ---------------- deterministic cluster compaction (single block) ----------------
// rowidx_c = rows with target in cluster c (ascending); posmap[row] = compact pos.

__global__ __launch_bounds__(256) void scan_compact(
    const int* __restrict__ target,
    int* __restrict__ r1, int* __restrict__ r2, int* __restrict__ r3,
    int* __restrict__ posmap, int* __restrict__ counts) {
  __shared__ unsigned long long sd[256];
  int t = threadIdx.x;
  int c1 = 0, c2 = 0, c3 = 0;
#pragma unroll
  for (int j = 0; j < 16; ++j) {
    int tt = target[t * 16 + j];
    if (tt >= 10000) { if (tt < 20000) ++c1; else if (tt < 40000) ++c2; else ++c3; }
  }
  unsigned long long packed = (unsigned long long)c1 |
                              ((unsigned long long)c2 << 21) |
                              ((unsigned long long)c3 << 42);
  sd[t] = packed;
  __syncthreads();
  for (int off = 1; off < 256; off <<= 1) {
    unsigned long long add = t >= off ? sd[t - off] : 0ULL;
    __syncthreads();
    sd[t] += add;
    __syncthreads();
  }
  unsigned long long excl = sd[t] - packed;
  const unsigned long long M21 = (1ULL << 21) - 1;
  int p1 = (int)(excl & M21), p2 = (int)((excl >> 21) & M21), p3 = (int)(excl >> 42);
#pragma unroll
  for (int j = 0; j < 16; ++j) {
    int row = t * 16 + j;
    int tt = target[row];
    if (tt >= 10000) {
      if (tt < 20000)      { r1[p1] = row; posmap[row] = p1; ++p1; }
      else if (tt < 40000) { r2[p2] = row; posmap[row] = p2; ++p2; }
      else                 { r3[p3] = row; posmap[row] = p3; ++p3; }
    }
  }
  if (t == 255) {
    unsigned long long tot = sd[255];
    counts[1] = (int)(tot & M21);
    counts[2] = (int)((tot >> 21) & M21);
    counts[3] = (int)(tot >> 42);
  }
}

// ---------------- staged 128x128 GEMM ----------------
// C = A[M,K] * B[Npad,K]^T (+bias). 256 thr = 4 waves, each wave one 64x64
// quadrant (4x4 frags of 16x16x32 MFMA). BK=32, global_load_lds staging.
// MODE 0: store bf16 C.
// MODE 1: fixed-ref LSE: per-lane sum of exp(logit-MREF) across this block's
//   tiles (no cross-lane work per tile); one 16-lane merge at block end.
//   Specials scattered directly. GATHER: A rows indirected through rowidx.

template<int K, int MODE, int NSPEC, bool GATHER>
__global__ __launch_bounds__(256, 3) void gemm128(
    const bf16* __restrict__ A, int lda,
    const bf16* __restrict__ B, int nTiles, int tpb,
    bf16* __restrict__ C, int ldc,
    const float* __restrict__ bias, const int* __restrict__ target,
    int specBase, int specClamp,
    float* __restrict__ Ps, int nslot, float* __restrict__ Pg,
    const int* __restrict__ rowidx, const int* __restrict__ counts, int cluster) {
  int wg = xcd_swz(blockIdx.x, gridDim.x);
  int split = wg >> 5;   // col-split major: per-XCD chunk keeps B slice L2-hot
  int rowblk = wg & 31;
  int rowbase = rowblk * 128;
  int nc = M_TOK;
  if (GATHER) {
    nc = counts[cluster];
    if (rowbase >= nc) return;   // block-uniform exit, before any barrier
  }
  int tid = threadIdx.x;
  int w = tid >> 6, llo = tid & 15, lhi = (tid >> 4) & 3;
  int wr = w >> 1, wc = w & 1;

  __shared__ bf16 As[128 * 32];
  __shared__ bf16 Bs[128 * 32];

  // staging addresses: thread t covers 16B at LDS byte t*16 (linear)
  int srow = tid >> 2;
  int selem = (tid & 3) * 8;
  int sr0 = rowbase + srow, sr1 = sr0 + 64;
  if (GATHER) {
    sr0 = rowidx[sr0 < nc ? sr0 : nc - 1];
    sr1 = rowidx[sr1 < nc ? sr1 : nc - 1];
  }
  const bf16* ga0 = A + (long)sr0 * lda + selem;
  const bf16* ga1 = A + (long)sr1 * lda + selem;
  bf16* la0 = As + tid * 8;
  bf16* la1 = As + 2048 + tid * 8;
  bf16* lb0 = Bs + tid * 8;
  bf16* lb1 = Bs + 2048 + tid * 8;

  float rs[4][4];
#pragma unroll
  for (int a = 0; a < 4; ++a)
#pragma unroll
    for (int b = 0; b < 4; ++b) rs[a][b] = 0.f;

  int t0 = split * tpb;
  int tE = t0 + tpb; if (tE > nTiles) tE = nTiles;

  for (int tile = t0; tile < tE; ++tile) {
    int col0 = tile * 128;
    const bf16* gb0 = B + (long)(col0 + srow) * K + selem;
    const bf16* gb1 = gb0 + (long)64 * K;

    f32x4 acc[4][4];
    f32x4 zero = {0.f, 0.f, 0.f, 0.f};
#pragma unroll
    for (int a = 0; a < 4; ++a)
#pragma unroll
      for (int b = 0; b < 4; ++b) acc[a][b] = zero;

    for (int k0 = 0; k0 < K; k0 += 32) {
      gl_lds16(ga0 + k0, la0);
      gl_lds16(ga1 + k0, la1);
      gl_lds16(gb0 + k0, lb0);
      gl_lds16(gb1 + k0, lb1);
      __syncthreads();
      bf16x8 af[4], bf_[4];
#pragma unroll
      for (int m = 0; m < 4; ++m)
        af[m] = *(const bf16x8*)(As + (wr * 64 + m * 16 + llo) * 32 + lhi * 8);
#pragma unroll
      for (int n = 0; n < 4; ++n)
        bf_[n] = *(const bf16x8*)(Bs + (wc * 64 + n * 16 + llo) * 32 + lhi * 8);
#pragma unroll
      for (int m = 0; m < 4; ++m)
#pragma unroll
        for (int n = 0; n < 4; ++n)
          acc[m][n] = __builtin_amdgcn_mfma_f32_16x16x32_bf16(af[m], bf_[n], acc[m][n], 0, 0, 0);
      __syncthreads();
    }

    if (MODE == 0) {
#pragma unroll
      for (int m = 0; m < 4; ++m) {
        int row = rowbase + wr * 64 + m * 16 + lhi * 4;
#pragma unroll
        for (int n = 0; n < 4; ++n) {
          int col = col0 + wc * 64 + n * 16 + llo;
#pragma unroll
          for (int r = 0; r < 4; ++r)
            C[(long)(row + r) * ldc + col] = (bf16)acc[m][n][r];
        }
      }
    } else {
      float bv[4];
#pragma unroll
      for (int n = 0; n < 4; ++n) bv[n] = bias[col0 + wc * 64 + n * 16 + llo];
#pragma unroll
      for (int mm = 0; mm < 4; ++mm) {
#pragma unroll
        for (int r = 0; r < 4; ++r) {
          int crow = rowbase + wr * 64 + mm * 16 + lhi * 4 + r;
          float v[4];
#pragma unroll
          for (int n = 0; n < 4; ++n) {
            v[n] = acc[mm][n][r] + bv[n];
            rs[mm][r] += __expf(v[n] - MREF);
          }
          int erow = crow;
          if (GATHER) erow = rowidx[crow < nc ? crow : nc - 1];
          int tg = target[erow] - specBase;
          int sc = tg < 0 ? 0 : (tg > specClamp ? specClamp : tg);
#pragma unroll
          for (int n = 0; n < 4; ++n) {
            int col = col0 + wc * 64 + n * 16 + llo;
            if (col == sc) Pg[erow] = v[n];
            if (NSPEC > 1) {
#pragma unroll
              for (int q = 1; q < NSPEC; ++q)
                if (col == 9999 + q) Pg[(long)q * M_TOK + erow] = v[n];
            }
          }
        }
      }
    }
  }

  if (MODE == 1) {
    // single 16-lane merge at block end; slot per (split, column-half wc)
#pragma unroll
    for (int mm = 0; mm < 4; ++mm) {
#pragma unroll
      for (int r = 0; r < 4; ++r) {
        float vv = rs[mm][r];
        vv += __shfl_xor(vv, 1);
        vv += __shfl_xor(vv, 2);
        vv += __shfl_xor(vv, 4);
        vv += __shfl_xor(vv, 8);
        if (llo == 0) {
          int crow = rowbase + wr * 64 + mm * 16 + lhi * 4 + r;
          Ps[(long)crow * nslot + (split * 2 + wc)] = vv;
        }
      }
    }
  }
}

// ---------------- merge partials -> per-token lp (wave per row) ----------------

__global__ __launch_bounds__(256) void merge_lp(
    const int* __restrict__ target, const int* __restrict__ posmap,
    const float* __restrict__ hs, int NSH, const float* __restrict__ hg,
    const float* __restrict__ s1, int NS1, const float* __restrict__ g1,
    const float* __restrict__ s2, int NS2, const float* __restrict__ g2,
    const float* __restrict__ s3, int NS3, const float* __restrict__ g3,
    float* __restrict__ lp) {
  int lane = threadIdx.x & 63;
  int row = (blockIdx.x * 256 + threadIdx.x) >> 6;
  if (row >= M_TOK) return;

  float sh = 0.f;
  for (int sp = lane; sp < NSH; sp += 64) sh += hs[(long)row * NSH + sp];
#pragma unroll
  for (int off = 1; off < 64; off <<= 1) sh += __shfl_xor(sh, off);
  float lseh = MREF + __logf(sh);

  int t = target[row];
  float res;
  if (t < 10000) {
    res = hg[row] - lseh;
  } else {
    const float* ts; const float* tg; int NS; int q;
    if (t < 20000)      { ts = s1; tg = g1; NS = NS1; q = 3; }
    else if (t < 40000) { ts = s2; tg = g2; NS = NS2; q = 2; }
    else                { ts = s3; tg = g3; NS = NS3; q = 1; }
    int pos = posmap[row];
    float ss = 0.f;
    for (int sp = lane; sp < NS; sp += 64) ss += ts[(long)pos * NS + sp];
#pragma unroll
    for (int off = 1; off < 64; off <<= 1) ss += __shfl_xor(ss, off);
    float lset = MREF + __logf(ss);
    res = (hg[(long)q * M_TOK + row] - lseh) + (tg[row] - lset);
  }
  if (lane == 0) lp[row] = res;
}

__global__ void neg_mean(const float* __restrict__ lp, float* __restrict__ out) {
  __shared__ float red[256];
  float s = 0.f;
  for (int i = threadIdx.x; i < M_TOK; i += 256) s += lp[i];
  red[threadIdx.x] = s;
  __syncthreads();
  for (int o = 128; o > 0; o >>= 1) {
    if (threadIdx.x < o) red[threadIdx.x] += red[threadIdx.x + o];
    __syncthreads();
  }
  if (threadIdx.x == 0) out[0] = -red[0] / (float)M_TOK;
}

// ---------------- host ----------------

extern "C" void kernel_launch(void* const* d_in, const int* in_sizes, int n_in,
                              void* d_out, int out_size, void* d_ws, size_t ws_size,
                              hipStream_t stream) {
  const float* hidden = (const float*)d_in[0];
  const int*   target = (const int*)d_in[1];
  const float* w0 = (const float*)d_in[2];
  const float* b0 = (const float*)d_in[3];
  const float* p0 = (const float*)d_in[4];
  const float* w1 = (const float*)d_in[5];
  const float* b1 = (const float*)d_in[6];
  const float* p1 = (const float*)d_in[7];
  const float* w2 = (const float*)d_in[8];
  const float* b2 = (const float*)d_in[9];
  const float* p2 = (const float*)d_in[10];
  const float* w3 = (const float*)d_in[11];
  const float* b3 = (const float*)d_in[12];
  const float* p3 = (const float*)d_in[13];
  const float* cw = (const float*)d_in[14];
  const float* cb = (const float*)d_in[15];

  const int NH = 10112, N1 = 10112, N2 = 20096, N3 = 10112;   // 128-padded cols
  const int TH = 79, T1t = 79, T2t = 157, T3t = 79;           // 128-col tiles
  // tiles-per-block and split counts
  const int TPB_H = 4, TPB_1 = 1, TPB_2 = 2, TPB_3 = 1;
  const int SH = (TH + TPB_H - 1) / TPB_H;    // 20 -> head grid 640 (all-resident @3/CU)
  const int S1 = (T1t + TPB_1 - 1) / TPB_1;   // 79
  const int S2 = (T2t + TPB_2 - 1) / TPB_2;   // 79
  const int S3 = (T3t + TPB_3 - 1) / TPB_3;   // 79
  const int NSH = SH * 2, NS1 = S1 * 2, NS2 = S2 * 2, NS3 = S3 * 2;
  const int NPB = 1408;                       // p0|p1|p2|p3 + pad

  char* ws = (char*)d_ws;
  size_t off = 0;
  auto alloc = [&](size_t bytes) -> char* {
    char* p = ws + off;
    off += (bytes + 255) & ~(size_t)255;
    return p;
  };
  bf16* hiddenB = (bf16*)alloc(4096L * 1024 * 2);
  bf16* pB    = (bf16*)alloc((long)NPB * 1024 * 2);
  bf16* headw = (bf16*)alloc((long)NH * 1024 * 2);
  bf16* w1p   = (bf16*)alloc((long)N1 * 256 * 2);
  bf16* w2p   = (bf16*)alloc((long)N2 * 64 * 2);
  bf16* w3p   = (bf16*)alloc((long)N3 * 32 * 2);
  bf16* proj  = (bf16*)alloc(4096L * NPB * 2);
  float* headb = (float*)alloc((long)NH * 4);
  float* t1b   = (float*)alloc((long)N1 * 4);
  float* t2b   = (float*)alloc((long)N2 * 4);
  float* t3b   = (float*)alloc((long)N3 * 4);
  float* hsP = (float*)alloc((size_t)M_TOK * NSH * 4);
  float* hg  = (float*)alloc(4L * M_TOK * 4);
  float* s1P = (float*)alloc((size_t)M_TOK * NS1 * 4);
  float* g1  = (float*)alloc((size_t)M_TOK * 4);
  float* s2P = (float*)alloc((size_t)M_TOK * NS2 * 4);
  float* g2  = (float*)alloc((size_t)M_TOK * 4);
  float* s3P = (float*)alloc((size_t)M_TOK * NS3 * 4);
  float* g3  = (float*)alloc((size_t)M_TOK * 4);
  float* lp  = (float*)alloc((size_t)M_TOK * 4);
  int* r1 = (int*)alloc((size_t)M_TOK * 4);
  int* r2 = (int*)alloc((size_t)M_TOK * 4);
  int* r3 = (int*)alloc((size_t)M_TOK * 4);
  int* posmap = (int*)alloc((size_t)M_TOK * 4);
  int* counts = (int*)alloc(16);
  if (ws_size < off) return;  // fail cleanly rather than corrupt

  // zero only the pad regions (everything else fully overwritten each call)
  hipMemsetAsync(headw + 10003L * 1024, 0, (NH - 10003L) * 1024 * 2, stream);
  hipMemsetAsync(w1p + 10000L * 256, 0, (N1 - 10000L) * 256 * 2, stream);
  hipMemsetAsync(w2p + 20000L * 64, 0, (N2 - 20000L) * 64 * 2, stream);
  hipMemsetAsync(w3p, 0, (long)N3 * 32 * 2, stream);
  hipMemsetAsync(pB + 1360L * 1024, 0, 48L * 1024 * 2, stream);

  // conversions
  cvt_lin<<<(4096 * 1024 / 4 + 255) / 256, 256, 0, stream>>>(hidden, hiddenB, 4096L * 1024 / 4);
  cvt_lin<<<(10000 * 1024 / 4 + 255) / 256, 256, 0, stream>>>(w0, headw, 10000L * 1024 / 4);
  cvt_lin<<<(3 * 1024 / 4 + 255) / 256, 256, 0, stream>>>(cw, headw + 10000L * 1024, 3L * 1024 / 4);
  cvt_lin<<<(10000 * 256 / 4 + 255) / 256, 256, 0, stream>>>(w1, w1p, 10000L * 256 / 4);
  cvt_lin<<<(20000 * 64 / 4 + 255) / 256, 256, 0, stream>>>(w2, w2p, 20000L * 64 / 4);
  cvt_w3k<<<(160000 + 255) / 256, 256, 0, stream>>>(w3, w3p);
  tr_cvt<<<dim3(16, 16), 256, 0, stream>>>(p0, pB, 1024);
  tr_cvt<<<dim3(16, 4), 256, 0, stream>>>(p1, pB + 1024L * 1024, 256);
  tr_cvt<<<dim3(16, 1), 256, 0, stream>>>(p2, pB + 1280L * 1024, 64);
  tr_cvt<<<dim3(16, 1), 256, 0, stream>>>(p3, pB + 1344L * 1024, 16);
  build_bias<<<(NH + N1 + N2 + N3 + 255) / 256, 256, 0, stream>>>(
      b0, cb, b1, b2, b3, headb, t1b, t2b, t3b, NH, N1, N2, N3);
  scan_compact<<<1, 256, 0, stream>>>(target, r1, r2, r3, posmap, counts);

  // fused projection GEMM: proj[4096][1408] = hiddenB @ [p0|p1|p2|p3]^T
  gemm128<1024, 0, 1, false><<<11 * 32, 256, 0, stream>>>(
      hiddenB, 1024, pB, 11, 1, proj, NPB,
      nullptr, nullptr, 0, 0, nullptr, 0, nullptr, nullptr, nullptr, 0);

  // head: logits over [proj @ headw^T + headb], fixed-ref LSE + gathers
  gemm128<1024, 1, 4, false><<<SH * 32, 256, 0, stream>>>(
      proj, NPB, headw, TH, TPB_H, nullptr, 0,
      headb, target, 0, 9999, hsP, NSH, hg, nullptr, nullptr, 0);

  // tails: compacted rows via gather
  gemm128<256, 1, 1, true><<<S1 * 32, 256, 0, stream>>>(
      proj + 1024, NPB, w1p, T1t, TPB_1, nullptr, 0,
      t1b, target, 10000, 9999, s1P, NS1, g1, r1, counts, 1);
  gemm128<64, 1, 1, true><<<S2 * 32, 256, 0, stream>>>(
      proj + 1280, NPB, w2p, T2t, TPB_2, nullptr, 0,
      t2b, target, 20000, 19999, s2P, NS2, g2, r2, counts, 2);
  gemm128<32, 1, 1, true><<<S3 * 32, 256, 0, stream>>>(
      proj + 1344, NPB, w3p, T3t, TPB_3, nullptr, 0,
      t3b, target, 40000, 9999, s3P, NS3, g3, r3, counts, 3);

  merge_lp<<<1024, 256, 0, stream>>>(target, posmap,
      hsP, NSH, hg, s1P, NS1, g1, s2P, NS2, g2, s3P, NS3, g3, lp);
  neg_mean<<<1, 256, 0, stream>>>(lp, (float*)d_out);
}

// Round 4
// 211.974 us; speedup vs baseline: 5.9384x; 1.3936x over previous
//
#include <hip/hip_runtime.h>
#include <hip/hip_fp8.h>
#include <math.h>

typedef __bf16 bf16;
typedef __attribute__((ext_vector_type(8))) __bf16 bf16x8;
typedef __attribute__((ext_vector_type(4))) float f32x4;
typedef __attribute__((ext_vector_type(16))) float f32x16;
typedef __attribute__((ext_vector_type(8))) int i32x8;

#define M_TOK 4096
#define MREF 8.0f   // fixed logsumexp reference (logits bounded ~|4|)

// ---------------- helpers ----------------

__device__ __forceinline__ void gl_lds16(const void* g, void* l) {
  __builtin_amdgcn_global_load_lds(
      (const __attribute__((address_space(1))) unsigned int*)g,
      (__attribute__((address_space(3))) unsigned int*)l, 16, 0, 0);
}

__device__ __forceinline__ int xcd_swz(int idx, int nwg) {
  int xcd = idx & 7, pos = idx >> 3;
  int q = nwg >> 3, r = nwg & 7;
  int base = xcd < r ? xcd * (q + 1) : r * (q + 1) + (xcd - r) * q;
  return base + pos;
}

__device__ __forceinline__ unsigned char f2fp8(float v) {
  __hip_fp8_e4m3 h(v);
  return (unsigned char)h.__x;
}
__device__ __forceinline__ float fp82f(unsigned char b) {
  __hip_fp8_e4m3 h;
  h.__x = (__hip_fp8_storage_t)b;
  return (float)h;
}

struct bf16x4s { bf16 a, b, c, d; };

// ---------------- fused prep kernel (all conversions + pads + biases) ----------------
// segments by blockIdx range; every destination byte (incl. pads) is written.

#define NB0 4096    // hidden f32 -> bf16            (4096*1024/4/256)
#define NB1 10240   // w0+cw -> headwF8 [10240][1024] fp8 (+zero pads)
#define NB2 2528    // w1 -> w1p [10112][256] bf16
#define NB3 5024    // w2 -> w2p [20096][64] bf16
#define NB4 316     // w3 -> w3p [10112][32] bf16 (K pad 16->32)
#define NB5 352     // p0..p3 transpose -> pB [1408][1024] bf16 (22 n-tiles x 16 k-tiles)
#define NB6 198     // biases (10240+10112+20096+10112 = 50560 elems)

__global__ __launch_bounds__(256) void prep(
    const float* __restrict__ hidden, const float* __restrict__ w0,
    const float* __restrict__ cw, const float* __restrict__ w1,
    const float* __restrict__ w2, const float* __restrict__ w3,
    const float* __restrict__ p0, const float* __restrict__ p1,
    const float* __restrict__ p2, const float* __restrict__ p3,
    const float* __restrict__ b0, const float* __restrict__ cb,
    const float* __restrict__ b1, const float* __restrict__ b2,
    const float* __restrict__ b3,
    bf16* __restrict__ hiddenB, unsigned char* __restrict__ headwF8,
    bf16* __restrict__ w1p, bf16* __restrict__ w2p, bf16* __restrict__ w3p,
    bf16* __restrict__ pB,
    float* __restrict__ headb, float* __restrict__ t1b,
    float* __restrict__ t2b, float* __restrict__ t3b) {
  __shared__ float tile[64][65];
  int b = blockIdx.x, t = threadIdx.x;
  if (b < NB0) {
    long i = (long)b * 256 + t;
    float4 v = ((const float4*)hidden)[i];
    bf16x4s o; o.a = (bf16)v.x; o.b = (bf16)v.y; o.c = (bf16)v.z; o.d = (bf16)v.w;
    ((bf16x4s*)hiddenB)[i] = o;
    return;
  }
  b -= NB0;
  if (b < NB1) {
    long i = (long)b * 256 + t;       // chunk of 4 elems
    int row = (int)(i >> 8), c4 = ((int)i & 255) * 4;
    float4 v;
    if (row < 10000)      v = *(const float4*)(w0 + (long)row * 1024 + c4);
    else if (row < 10003) v = *(const float4*)(cw + (long)(row - 10000) * 1024 + c4);
    else                  v = make_float4(0.f, 0.f, 0.f, 0.f);
    unsigned int u = (unsigned int)f2fp8(v.x) | ((unsigned int)f2fp8(v.y) << 8) |
                     ((unsigned int)f2fp8(v.z) << 16) | ((unsigned int)f2fp8(v.w) << 24);
    ((unsigned int*)headwF8)[i] = u;
    return;
  }
  b -= NB1;
  if (b < NB2) {
    long i = (long)b * 256 + t;
    int row = (int)(i >> 6), c4 = ((int)i & 63) * 4;
    float4 v = row < 10000 ? *(const float4*)(w1 + (long)row * 256 + c4)
                           : make_float4(0.f, 0.f, 0.f, 0.f);
    bf16x4s o; o.a = (bf16)v.x; o.b = (bf16)v.y; o.c = (bf16)v.z; o.d = (bf16)v.w;
    ((bf16x4s*)w1p)[i] = o;
    return;
  }
  b -= NB2;
  if (b < NB3) {
    long i = (long)b * 256 + t;
    int row = (int)(i >> 4), c4 = ((int)i & 15) * 4;
    float4 v = row < 20000 ? *(const float4*)(w2 + (long)row * 64 + c4)
                           : make_float4(0.f, 0.f, 0.f, 0.f);
    bf16x4s o; o.a = (bf16)v.x; o.b = (bf16)v.y; o.c = (bf16)v.z; o.d = (bf16)v.w;
    ((bf16x4s*)w2p)[i] = o;
    return;
  }
  b -= NB3;
  if (b < NB4) {
    long i = (long)b * 256 + t;
    int row = (int)(i >> 3), c4 = ((int)i & 7) * 4;
    float4 v = (row < 10000 && c4 < 16) ? *(const float4*)(w3 + (long)row * 16 + c4)
                                        : make_float4(0.f, 0.f, 0.f, 0.f);
    bf16x4s o; o.a = (bf16)v.x; o.b = (bf16)v.y; o.c = (bf16)v.z; o.d = (bf16)v.w;
    ((bf16x4s*)w3p)[i] = o;
    return;
  }
  b -= NB4;
  if (b < NB5) {
    int tk = b & 15, tn = b >> 4;
    int kb = tk * 64, nb = tn * 64;
    const float* src; int N, segn;
    if (tn < 16)      { src = p0; N = 1024; segn = nb; }
    else if (tn < 20) { src = p1; N = 256;  segn = nb - 1024; }
    else if (tn < 21) { src = p2; N = 64;   segn = 0; }
    else              { src = p3; N = 16;   segn = 0; }
    int tx = t & 63, ty = t >> 6;
#pragma unroll
    for (int kk = ty; kk < 64; kk += 4)
      tile[kk][tx] = (segn + tx < N) ? src[(long)(kb + kk) * N + segn + tx] : 0.f;
    __syncthreads();
#pragma unroll
    for (int nn = ty; nn < 64; nn += 4)
      pB[(long)(nb + nn) * 1024 + kb + tx] = (bf16)tile[tx][nn];
    return;
  }
  b -= NB5;
  {
    int i = b * 256 + t;
    if (i < 10240) {
      headb[i] = i < 10000 ? b0[i] : (i < 10003 ? cb[i - 10000] : -3.0e38f);
    } else if (i < 10240 + 10112) {
      int j = i - 10240; t1b[j] = j < 10000 ? b1[j] : -3.0e38f;
    } else if (i < 10240 + 10112 + 20096) {
      int j = i - 10240 - 10112; t2b[j] = j < 20000 ? b2[j] : -3.0e38f;
    } else if (i < 10240 + 10112 + 20096 + 10112) {
      int j = i - 10240 - 10112 - 20096; t3b[j] = j < 10000 ? b3[j] : -3.0e38f;
    }
  }
}

// ---------------- deterministic cluster compaction (single block) ----------------

__global__ __launch_bounds__(256) void scan_compact(
    const int* __restrict__ target,
    int* __restrict__ r1, int* __restrict__ r2, int* __restrict__ r3,
    int* __restrict__ posmap, int* __restrict__ counts) {
  __shared__ unsigned long long sd[256];
  int t = threadIdx.x;
  int c1 = 0, c2 = 0, c3 = 0;
#pragma unroll
  for (int j = 0; j < 16; ++j) {
    int tt = target[t * 16 + j];
    if (tt >= 10000) { if (tt < 20000) ++c1; else if (tt < 40000) ++c2; else ++c3; }
  }
  unsigned long long packed = (unsigned long long)c1 |
                              ((unsigned long long)c2 << 21) |
                              ((unsigned long long)c3 << 42);
  sd[t] = packed;
  __syncthreads();
  for (int off = 1; off < 256; off <<= 1) {
    unsigned long long add = t >= off ? sd[t - off] : 0ULL;
    __syncthreads();
    sd[t] += add;
    __syncthreads();
  }
  unsigned long long excl = sd[t] - packed;
  const unsigned long long M21 = (1ULL << 21) - 1;
  int p1 = (int)(excl & M21), p2 = (int)((excl >> 21) & M21), p3 = (int)(excl >> 42);
#pragma unroll
  for (int j = 0; j < 16; ++j) {
    int row = t * 16 + j;
    int tt = target[row];
    if (tt >= 10000) {
      if (tt < 20000)      { r1[p1] = row; posmap[row] = p1; ++p1; }
      else if (tt < 40000) { r2[p2] = row; posmap[row] = p2; ++p2; }
      else                 { r3[p3] = row; posmap[row] = p3; ++p3; }
    }
  }
  if (t == 255) {
    unsigned long long tot = sd[255];
    counts[1] = (int)(tot & M21);
    counts[2] = (int)((tot >> 21) & M21);
    counts[3] = (int)(tot >> 42);
  }
}

// ---------------- bf16 staged 128x128 GEMM (proj + tails; verified structure) ----------------

template<int K, int MODE, int NSPEC, bool GATHER>
__global__ __launch_bounds__(256, 3) void gemm128(
    const bf16* __restrict__ A, int lda,
    const bf16* __restrict__ B, int nTiles, int tpb,
    bf16* __restrict__ C, int ldc,
    unsigned char* __restrict__ Cf8, int fp8Tiles,
    const float* __restrict__ bias, const int* __restrict__ target,
    int specBase, int specClamp,
    float* __restrict__ Ps, int nslot, float* __restrict__ Pg,
    const int* __restrict__ rowidx, const int* __restrict__ counts, int cluster) {
  int wg = xcd_swz(blockIdx.x, gridDim.x);
  int split = wg >> 5;
  int rowblk = wg & 31;
  int rowbase = rowblk * 128;
  int nc = M_TOK;
  if (GATHER) {
    nc = counts[cluster];
    if (rowbase >= nc) return;   // block-uniform exit, before any barrier
  }
  int tid = threadIdx.x;
  int w = tid >> 6, llo = tid & 15, lhi = (tid >> 4) & 3;
  int wr = w >> 1, wc = w & 1;

  __shared__ __align__(16) bf16 As[128 * 32];
  __shared__ __align__(16) bf16 Bs[128 * 32];

  int srow = tid >> 2;
  int selem = (tid & 3) * 8;
  int sr0 = rowbase + srow, sr1 = sr0 + 64;
  if (GATHER) {
    sr0 = rowidx[sr0 < nc ? sr0 : nc - 1];
    sr1 = rowidx[sr1 < nc ? sr1 : nc - 1];
  }
  const bf16* ga0 = A + (long)sr0 * lda + selem;
  const bf16* ga1 = A + (long)sr1 * lda + selem;
  bf16* la0 = As + tid * 8;
  bf16* la1 = As + 2048 + tid * 8;
  bf16* lb0 = Bs + tid * 8;
  bf16* lb1 = Bs + 2048 + tid * 8;

  float rs[4][4];
#pragma unroll
  for (int a = 0; a < 4; ++a)
#pragma unroll
    for (int bq = 0; bq < 4; ++bq) rs[a][bq] = 0.f;

  int t0 = split * tpb;
  int tE = t0 + tpb; if (tE > nTiles) tE = nTiles;

  for (int tile = t0; tile < tE; ++tile) {
    int col0 = tile * 128;
    const bf16* gb0 = B + (long)(col0 + srow) * K + selem;
    const bf16* gb1 = gb0 + (long)64 * K;

    f32x4 acc[4][4];
    f32x4 zero = {0.f, 0.f, 0.f, 0.f};
#pragma unroll
    for (int a = 0; a < 4; ++a)
#pragma unroll
      for (int bq = 0; bq < 4; ++bq) acc[a][bq] = zero;

    for (int k0 = 0; k0 < K; k0 += 32) {
      gl_lds16(ga0 + k0, la0);
      gl_lds16(ga1 + k0, la1);
      gl_lds16(gb0 + k0, lb0);
      gl_lds16(gb1 + k0, lb1);
      __syncthreads();
      bf16x8 af[4], bf_[4];
#pragma unroll
      for (int m = 0; m < 4; ++m)
        af[m] = *(const bf16x8*)(As + (wr * 64 + m * 16 + llo) * 32 + lhi * 8);
#pragma unroll
      for (int n = 0; n < 4; ++n)
        bf_[n] = *(const bf16x8*)(Bs + (wc * 64 + n * 16 + llo) * 32 + lhi * 8);
#pragma unroll
      for (int m = 0; m < 4; ++m)
#pragma unroll
        for (int n = 0; n < 4; ++n)
          acc[m][n] = __builtin_amdgcn_mfma_f32_16x16x32_bf16(af[m], bf_[n], acc[m][n], 0, 0, 0);
      __syncthreads();
    }

    if (MODE == 0) {
      if (tile < fp8Tiles) {
#pragma unroll
        for (int m = 0; m < 4; ++m) {
          int row = rowbase + wr * 64 + m * 16 + lhi * 4;
#pragma unroll
          for (int n = 0; n < 4; ++n) {
            int col = col0 + wc * 64 + n * 16 + llo;
#pragma unroll
            for (int r = 0; r < 4; ++r)
              Cf8[(long)(row + r) * 1024 + col] = f2fp8(acc[m][n][r]);
          }
        }
      } else {
#pragma unroll
        for (int m = 0; m < 4; ++m) {
          int row = rowbase + wr * 64 + m * 16 + lhi * 4;
#pragma unroll
          for (int n = 0; n < 4; ++n) {
            int col = col0 + wc * 64 + n * 16 + llo - fp8Tiles * 128;
#pragma unroll
            for (int r = 0; r < 4; ++r)
              C[(long)(row + r) * ldc + col] = (bf16)acc[m][n][r];
          }
        }
      }
    } else {
      float bv[4];
#pragma unroll
      for (int n = 0; n < 4; ++n) bv[n] = bias[col0 + wc * 64 + n * 16 + llo];
#pragma unroll
      for (int mm = 0; mm < 4; ++mm) {
#pragma unroll
        for (int r = 0; r < 4; ++r) {
          int crow = rowbase + wr * 64 + mm * 16 + lhi * 4 + r;
          float v[4];
#pragma unroll
          for (int n = 0; n < 4; ++n) {
            v[n] = acc[mm][n][r] + bv[n];
            rs[mm][r] += __expf(v[n] - MREF);
          }
          int erow = crow;
          if (GATHER) erow = rowidx[crow < nc ? crow : nc - 1];
          int tg = target[erow] - specBase;
          int sc = tg < 0 ? 0 : (tg > specClamp ? specClamp : tg);
#pragma unroll
          for (int n = 0; n < 4; ++n) {
            int col = col0 + wc * 64 + n * 16 + llo;
            if (col == sc) Pg[erow] = v[n];
          }
        }
      }
    }
  }

  if (MODE == 1) {
#pragma unroll
    for (int mm = 0; mm < 4; ++mm) {
#pragma unroll
      for (int r = 0; r < 4; ++r) {
        float vv = rs[mm][r];
        vv += __shfl_xor(vv, 1);
        vv += __shfl_xor(vv, 2);
        vv += __shfl_xor(vv, 4);
        vv += __shfl_xor(vv, 8);
        if (llo == 0) {
          int crow = rowbase + wr * 64 + mm * 16 + lhi * 4 + r;
          Ps[(long)crow * nslot + (split * 2 + wc)] = vv;
        }
      }
    }
  }
}

// ---------------- head: MX-fp8 128x128 staged GEMM + fixed-ref LSE ----------------
// A [4096][1024] fp8, B [10240][1024] fp8. 4 waves 2x2, wave = 64x64 = 2x2 of
// 32x32x64 scaled MFMA (scales = 1.0). 2-phase sync (verified structure).
// LDS rows 64B with XOR slot-swizzle (involution, pre-swizzled global source).

template<int TPB>
__global__ __launch_bounds__(256, 3) void head_lse_fp8(
    const unsigned char* __restrict__ A,
    const unsigned char* __restrict__ B,
    const float* __restrict__ bias,
    float* __restrict__ Ps, int nTiles) {
  int nsplits = (nTiles + TPB - 1) / TPB;
  int wg = xcd_swz(blockIdx.x, gridDim.x);
  int split = wg >> 5, rowblk = wg & 31;
  int rowbase = rowblk * 128;
  int tid = threadIdx.x;
  int w = tid >> 6, l = tid & 63;
  int l31 = l & 31, lh = l >> 5;
  int wr = w >> 1, wc = w & 1;

  __shared__ __align__(16) unsigned char As[128 * 64];
  __shared__ __align__(16) unsigned char Bs[128 * 64];

  // staging: thread t -> LDS 16B slot t of each half (rows 0-63 / 64-127).
  // LDS[row][s] holds G[row][s ^ f(row)], f(row) = (row ^ (row>>2)) & 3.
  int srow = tid >> 2;
  int gslot = (tid & 3) ^ ((srow ^ (srow >> 2)) & 3);
  const unsigned char* ga0 = A + (long)(rowbase + srow) * 1024 + gslot * 16;
  const unsigned char* ga1 = ga0 + 64L * 1024;
  unsigned char* la0 = As + tid * 16;
  unsigned char* la1 = As + 4096 + tid * 16;
  unsigned char* lb0 = Bs + tid * 16;
  unsigned char* lb1 = Bs + 4096 + tid * 16;

  float rs[2][16];
#pragma unroll
  for (int m = 0; m < 2; ++m)
#pragma unroll
    for (int g = 0; g < 16; ++g) rs[m][g] = 0.f;

  int t0 = split * TPB;
  int tE = t0 + TPB; if (tE > nTiles) tE = nTiles;

  for (int tile = t0; tile < tE; ++tile) {
    const unsigned char* gb0 = B + (long)(tile * 128 + srow) * 1024 + gslot * 16;
    const unsigned char* gb1 = gb0 + 64L * 1024;

    f32x16 acc[2][2];
#pragma unroll
    for (int m = 0; m < 2; ++m)
#pragma unroll
      for (int n = 0; n < 2; ++n)
#pragma unroll
        for (int g = 0; g < 16; ++g) acc[m][n][g] = 0.f;

    for (int k0 = 0; k0 < 1024; k0 += 64) {
      gl_lds16(ga0 + k0, la0);
      gl_lds16(ga1 + k0, la1);
      gl_lds16(gb0 + k0, lb0);
      gl_lds16(gb1 + k0, lb1);
      __syncthreads();
      i32x8 af[2], bfr[2];
#pragma unroll
      for (int m = 0; m < 2; ++m) {
        int ar = wr * 64 + m * 32 + l31;
        int s0 = (lh * 2) ^ ((ar ^ (ar >> 2)) & 3);
        int4 lo = *(const int4*)(As + ar * 64 + s0 * 16);
        int4 hi = *(const int4*)(As + ar * 64 + (s0 ^ 1) * 16);
        af[m][0] = lo.x; af[m][1] = lo.y; af[m][2] = lo.z; af[m][3] = lo.w;
        af[m][4] = hi.x; af[m][5] = hi.y; af[m][6] = hi.z; af[m][7] = hi.w;
      }
#pragma unroll
      for (int n = 0; n < 2; ++n) {
        int br = wc * 64 + n * 32 + l31;
        int s0 = (lh * 2) ^ ((br ^ (br >> 2)) & 3);
        int4 lo = *(const int4*)(Bs + br * 64 + s0 * 16);
        int4 hi = *(const int4*)(Bs + br * 64 + (s0 ^ 1) * 16);
        bfr[n][0] = lo.x; bfr[n][1] = lo.y; bfr[n][2] = lo.z; bfr[n][3] = lo.w;
        bfr[n][4] = hi.x; bfr[n][5] = hi.y; bfr[n][6] = hi.z; bfr[n][7] = hi.w;
      }
#pragma unroll
      for (int m = 0; m < 2; ++m)
#pragma unroll
        for (int n = 0; n < 2; ++n)
          acc[m][n] = __builtin_amdgcn_mfma_scale_f32_32x32x64_f8f6f4(
              af[m], bfr[n], acc[m][n], 0, 0, 0, 0x7F7F7F7F, 0, 0x7F7F7F7F);
      __syncthreads();
    }

    // epilogue: bias + exp-accumulate (no cross-lane work per tile)
    int col0 = tile * 128;
#pragma unroll
    for (int n = 0; n < 2; ++n) {
      float bv = bias[col0 + wc * 64 + n * 32 + l31];
#pragma unroll
      for (int m = 0; m < 2; ++m)
#pragma unroll
        for (int g = 0; g < 16; ++g)
          rs[m][g] += __expf(acc[m][n][g] + bv - MREF);
    }
  }

  // one cross-lane merge at block end (32 col-lanes share rows)
#pragma unroll
  for (int m = 0; m < 2; ++m)
#pragma unroll
    for (int g = 0; g < 16; ++g) {
      float v = rs[m][g];
      v += __shfl_xor(v, 1);
      v += __shfl_xor(v, 2);
      v += __shfl_xor(v, 4);
      v += __shfl_xor(v, 8);
      v += __shfl_xor(v, 16);
      rs[m][g] = v;
    }
  if (l31 == 0) {
    int slot = split * 2 + wc;
#pragma unroll
    for (int m = 0; m < 2; ++m)
#pragma unroll
      for (int g = 0; g < 16; ++g) {
        int row = rowbase + wr * 64 + m * 32 + (g & 3) + 8 * (g >> 2) + 4 * lh;
        Ps[(long)row * (nsplits * 2) + slot] = rs[m][g];
      }
  }
}

// ---------------- head specials: 4 dots per row (target col + 3 cluster cols) ----------------

__global__ __launch_bounds__(256) void head_gather(
    const unsigned char* __restrict__ A, const unsigned char* __restrict__ W,
    const float* __restrict__ bias, const int* __restrict__ target,
    float* __restrict__ hg) {
  int row = (blockIdx.x * 256 + threadIdx.x) >> 6;
  int lane = threadIdx.x & 63;
  if (row >= M_TOK) return;
  const unsigned char* ap = A + (long)row * 1024 + lane * 16;
  float a[16];
#pragma unroll
  for (int j = 0; j < 16; ++j) a[j] = fp82f(ap[j]);
  int t = target[row];
  int c0 = t < 10000 ? t : 9999;
#pragma unroll
  for (int q = 0; q < 4; ++q) {
    int col = q == 0 ? c0 : 9999 + q;
    const unsigned char* wp = W + (long)col * 1024 + lane * 16;
    float d = 0.f;
#pragma unroll
    for (int j = 0; j < 16; ++j) d += a[j] * fp82f(wp[j]);
#pragma unroll
    for (int off = 1; off < 64; off <<= 1) d += __shfl_xor(d, off);
    if (lane == 0) hg[(long)q * M_TOK + row] = d + bias[col];
  }
}

// ---------------- merge partials -> per-token lp (wave per row) ----------------

__global__ __launch_bounds__(256) void merge_lp(
    const int* __restrict__ target, const int* __restrict__ posmap,
    const float* __restrict__ hs, int NSH, const float* __restrict__ hg,
    const float* __restrict__ s1, int NS1, const float* __restrict__ g1,
    const float* __restrict__ s2, int NS2, const float* __restrict__ g2,
    const float* __restrict__ s3, int NS3, const float* __restrict__ g3,
    float* __restrict__ lp) {
  int lane = threadIdx.x & 63;
  int row = (blockIdx.x * 256 + threadIdx.x) >> 6;
  if (row >= M_TOK) return;

  float sh = 0.f;
  for (int sp = lane; sp < NSH; sp += 64) sh += hs[(long)row * NSH + sp];
#pragma unroll
  for (int off = 1; off < 64; off <<= 1) sh += __shfl_xor(sh, off);
  float lseh = MREF + __logf(sh);

  int t = target[row];
  float res;
  if (t < 10000) {
    res = hg[row] - lseh;
  } else {
    const float* ts; const float* tg; int NS; int q;
    if (t < 20000)      { ts = s1; tg = g1; NS = NS1; q = 3; }
    else if (t < 40000) { ts = s2; tg = g2; NS = NS2; q = 2; }
    else                { ts = s3; tg = g3; NS = NS3; q = 1; }
    int pos = posmap[row];
    float ss = 0.f;
    for (int sp = lane; sp < NS; sp += 64) ss += ts[(long)pos * NS + sp];
#pragma unroll
    for (int off = 1; off < 64; off <<= 1) ss += __shfl_xor(ss, off);
    float lset = MREF + __logf(ss);
    res = (hg[(long)q * M_TOK + row] - lseh) + (tg[row] - lset);
  }
  if (lane == 0) lp[row] = res;
}

__global__ void neg_mean(const float* __restrict__ lp, float* __restrict__ out) {
  __shared__ float red[256];
  float s = 0.f;
  for (int i = threadIdx.x; i < M_TOK; i += 256) s += lp[i];
  red[threadIdx.x] = s;
  __syncthreads();
  for (int o = 128; o > 0; o >>= 1) {
    if (threadIdx.x < o) red[threadIdx.x] += red[threadIdx.x + o];
    __syncthreads();
  }
  if (threadIdx.x == 0) out[0] = -red[0] / (float)M_TOK;
}

// ---------------- host ----------------

extern "C" void kernel_launch(void* const* d_in, const int* in_sizes, int n_in,
                              void* d_out, int out_size, void* d_ws, size_t ws_size,
                              hipStream_t stream) {
  const float* hidden = (const float*)d_in[0];
  const int*   target = (const int*)d_in[1];
  const float* w0 = (const float*)d_in[2];
  const float* b0 = (const float*)d_in[3];
  const float* p0 = (const float*)d_in[4];
  const float* w1 = (const float*)d_in[5];
  const float* b1 = (const float*)d_in[6];
  const float* p1 = (const float*)d_in[7];
  const float* w2 = (const float*)d_in[8];
  const float* b2 = (const float*)d_in[9];
  const float* p2 = (const float*)d_in[10];
  const float* w3 = (const float*)d_in[11];
  const float* b3 = (const float*)d_in[12];
  const float* p3 = (const float*)d_in[13];
  const float* cw = (const float*)d_in[14];
  const float* cb = (const float*)d_in[15];

  const int NH = 10240;                       // head cols, 128-padded (fp8 path)
  const int N1 = 10112, N2 = 20096, N3 = 10112;
  const int TH = NH / 128;                    // 80
  const int T1t = 79, T2t = 157, T3t = 79;
  const int TPB_H = 4, TPB_1 = 1, TPB_2 = 2, TPB_3 = 1;
  const int SH = TH / TPB_H;                  // 20
  const int S1 = 79, S2 = 79, S3 = 79;
  const int NSH = SH * 2, NS1 = S1 * 2, NS2 = S2 * 2, NS3 = S3 * 2;

  char* ws = (char*)d_ws;
  size_t off = 0;
  auto alloc = [&](size_t bytes) -> char* {
    char* p = ws + off;
    off += (bytes + 255) & ~(size_t)255;
    return p;
  };
  bf16* hiddenB = (bf16*)alloc(4096L * 1024 * 2);
  bf16* pB    = (bf16*)alloc(1408L * 1024 * 2);
  unsigned char* headwF8 = (unsigned char*)alloc((long)NH * 1024);
  bf16* w1p   = (bf16*)alloc((long)N1 * 256 * 2);
  bf16* w2p   = (bf16*)alloc((long)N2 * 64 * 2);
  bf16* w3p   = (bf16*)alloc((long)N3 * 32 * 2);
  unsigned char* projF8 = (unsigned char*)alloc(4096L * 1024);
  bf16* projT = (bf16*)alloc(4096L * 384 * 2);
  float* headb = (float*)alloc((long)NH * 4);
  float* t1b   = (float*)alloc((long)N1 * 4);
  float* t2b   = (float*)alloc((long)N2 * 4);
  float* t3b   = (float*)alloc((long)N3 * 4);
  float* hsP = (float*)alloc((size_t)M_TOK * NSH * 4);
  float* hg  = (float*)alloc(4L * M_TOK * 4);
  float* s1P = (float*)alloc((size_t)M_TOK * NS1 * 4);
  float* g1  = (float*)alloc((size_t)M_TOK * 4);
  float* s2P = (float*)alloc((size_t)M_TOK * NS2 * 4);
  float* g2  = (float*)alloc((size_t)M_TOK * 4);
  float* s3P = (float*)alloc((size_t)M_TOK * NS3 * 4);
  float* g3  = (float*)alloc((size_t)M_TOK * 4);
  float* lp  = (float*)alloc((size_t)M_TOK * 4);
  int* r1 = (int*)alloc((size_t)M_TOK * 4);
  int* r2 = (int*)alloc((size_t)M_TOK * 4);
  int* r3 = (int*)alloc((size_t)M_TOK * 4);
  int* posmap = (int*)alloc((size_t)M_TOK * 4);
  int* counts = (int*)alloc(16);
  if (ws_size < off) return;  // fail cleanly rather than corrupt

  // one fused prep kernel: all conversions, transposes, pads, biases
  const int PREP_BLOCKS = NB0 + NB1 + NB2 + NB3 + NB4 + NB5 + NB6;
  prep<<<PREP_BLOCKS, 256, 0, stream>>>(
      hidden, w0, cw, w1, w2, w3, p0, p1, p2, p3, b0, cb, b1, b2, b3,
      hiddenB, headwF8, w1p, w2p, w3p, pB, headb, t1b, t2b, t3b);
  scan_compact<<<1, 256, 0, stream>>>(target, r1, r2, r3, posmap, counts);

  // projection: proj = hiddenB @ [p0|p1|p2|p3]^T ; cols<1024 -> fp8, rest -> bf16
  gemm128<1024, 0, 1, false><<<11 * 32, 256, 0, stream>>>(
      hiddenB, 1024, pB, 11, 1, projT, 384, projF8, 8,
      nullptr, nullptr, 0, 0, nullptr, 0, nullptr, nullptr, nullptr, 0);

  // head: MX-fp8 GEMM + fixed-ref LSE partials
  head_lse_fp8<TPB_H><<<SH * 32, 256, 0, stream>>>(
      projF8, headwF8, headb, hsP, TH);
  head_gather<<<M_TOK / 4, 256, 0, stream>>>(projF8, headwF8, headb, target, hg);

  // tails: compacted rows via gather (bf16, verified path)
  gemm128<256, 1, 1, true><<<S1 * 32, 256, 0, stream>>>(
      projT, 384, w1p, T1t, TPB_1, nullptr, 0, nullptr, 0,
      t1b, target, 10000, 9999, s1P, NS1, g1, r1, counts, 1);
  gemm128<64, 1, 1, true><<<S2 * 32, 256, 0, stream>>>(
      projT + 256, 384, w2p, T2t, TPB_2, nullptr, 0, nullptr, 0,
      t2b, target, 20000, 19999, s2P, NS2, g2, r2, counts, 2);
  gemm128<32, 1, 1, true><<<S3 * 32, 256, 0, stream>>>(
      projT + 320, 384, w3p, T3t, TPB_3, nullptr, 0, nullptr, 0,
      t3b, target, 40000, 9999, s3P, NS3, g3, r3, counts, 3);

  merge_lp<<<1024, 256, 0, stream>>>(target, posmap,
      hsP, NSH, hg, s1P, NS1, g1, s2P, NS2, g2, s3P, NS3, g3, lp);
  neg_mean<<<1, 256, 0, stream>>>(lp, (float*)d_out);
}